// Round 4
// baseline (138.950 us; speedup 1.0000x reference)
//
#include <hip/hip_runtime.h>

// Fuzzy decoder: num[p,s,o] = max_k min(t0[s,k], t_p[k,o]); out = t + num - t*num.
// S=K=O=512, p in {0,1}. Packed-fp16 semiring GEMM (v_pk_min/v_pk_max), fp32 epilogue.
// K split 4 ways across blocks for occupancy (4 waves/SIMD); fp16 partial maxes in d_ws;
// second kernel reduces partials + fused amalgamate.

#define SDIM 512
#define TS 64      // s-tile per block
#define TO 32      // o-tile per block
#define SPLIT 4    // K-split factor
#define KB 128     // K per block
#define BK 64      // K per chunk
#define BK2 32     // packed k-pairs per chunk
#define NCH (KB / BK)   // 2 chunks

typedef _Float16 h2 __attribute__((ext_vector_type(2)));

__device__ __forceinline__ h2 pack2(float a, float b) {
    return __builtin_bit_cast(h2, __builtin_amdgcn_cvt_pkrtz(a, b));  // v_cvt_pkrtz_f16_f32
}
__device__ __forceinline__ h2 pmin(h2 a, h2 b) { return __builtin_elementwise_min(a, b); }
__device__ __forceinline__ h2 pmax(h2 a, h2 b) { return __builtin_elementwise_max(a, b); }
__device__ __forceinline__ h2 bch2(unsigned u) { return __builtin_bit_cast(h2, u); }

__global__ __launch_bounds__(256, 4) void compose_part(
        const float* __restrict__ t, _Float16* __restrict__ part) {
    // A tile TRANSPOSED: AlsT[k2][s] -> inner-loop read is one b128 (4 rows)
    __shared__ h2 AlsT[BK2][TS];
    // B tile: Bls[k2][o] -> inner-loop read is one b64 (2 cols)
    __shared__ h2 Bls[BK2][TO];

    const int tid = threadIdx.x;
    const int o0 = blockIdx.x * TO;          // 16 o-tiles
    const int s0 = blockIdx.y * TS;          // 8 s-tiles
    const int p  = blockIdx.z >> 2;          // predicate
    const int sp = blockIdx.z & 3;           // K-split index
    const int kbase = sp * KB;

    const float* __restrict__ B = t + p * (SDIM * SDIM);

    // compute mapping: 4 s-rows x 2 o-cols per thread
    const int ol = (tid & 15) * 2, sl = (tid >> 4) * 4;
    // staging A: row ar, k-quad aq (16 floats = 4 float4 along k)
    const int ar = tid >> 2, aq = tid & 3;
    // staging B: k-pair bk, o-quad bq
    const int bk = tid >> 3, bq = tid & 7;

    const float4* __restrict__ Arow =
        reinterpret_cast<const float4*>(t + (s0 + ar) * SDIM + kbase);

    h2 acc[4][2];
    #pragma unroll
    for (int j = 0; j < 4; ++j) {
        acc[j][0] = pack2(0.f, 0.f);
        acc[j][1] = pack2(0.f, 0.f);
    }

    float4 fa[4], fx, fy;
    // prologue: load chunk 0
    #pragma unroll
    for (int q4 = 0; q4 < 4; ++q4) fa[q4] = Arow[aq * 4 + q4];
    fx = *reinterpret_cast<const float4*>(B + (kbase + 2 * bk) * SDIM + o0 + bq * 4);
    fy = *reinterpret_cast<const float4*>(B + (kbase + 2 * bk + 1) * SDIM + o0 + bq * 4);

    #pragma unroll
    for (int c = 0; c < NCH; ++c) {
        // staged regs -> LDS
        #pragma unroll
        for (int q4 = 0; q4 < 4; ++q4) {
            const int k2 = aq * 8 + q4 * 2;
            AlsT[k2 + 0][ar] = pack2(fa[q4].x, fa[q4].y);
            AlsT[k2 + 1][ar] = pack2(fa[q4].z, fa[q4].w);
        }
        {
            h2 b0 = pack2(fx.x, fy.x), b1 = pack2(fx.y, fy.y);
            h2 b2 = pack2(fx.z, fy.z), b3 = pack2(fx.w, fy.w);
            uint4 u;
            u.x = __builtin_bit_cast(unsigned, b0);
            u.y = __builtin_bit_cast(unsigned, b1);
            u.z = __builtin_bit_cast(unsigned, b2);
            u.w = __builtin_bit_cast(unsigned, b3);
            *reinterpret_cast<uint4*>(&Bls[bk][bq * 4]) = u;  // one b128 store
        }
        __syncthreads();

        // prefetch next chunk (overlaps with compute below)
        if (c + 1 < NCH) {
            const int k0 = (c + 1) * BK;
            #pragma unroll
            for (int q4 = 0; q4 < 4; ++q4) fa[q4] = Arow[k0 / 4 + aq * 4 + q4];
            fx = *reinterpret_cast<const float4*>(B + (kbase + k0 + 2 * bk) * SDIM + o0 + bq * 4);
            fy = *reinterpret_cast<const float4*>(B + (kbase + k0 + 2 * bk + 1) * SDIM + o0 + bq * 4);
        }

        // max-min inner loop: per k2 = 1 b128 (A) + 1 b64 (B) + 16 pk instrs
        #pragma unroll
        for (int k2 = 0; k2 < BK2; ++k2) {
            const uint4 ua = *reinterpret_cast<const uint4*>(&AlsT[k2][sl]);
            const uint2 ub = *reinterpret_cast<const uint2*>(&Bls[k2][ol]);
            const h2 b0 = bch2(ub.x), b1 = bch2(ub.y);
            const h2 a0 = bch2(ua.x), a1 = bch2(ua.y), a2 = bch2(ua.z), a3 = bch2(ua.w);
            acc[0][0] = pmax(acc[0][0], pmin(a0, b0));
            acc[0][1] = pmax(acc[0][1], pmin(a0, b1));
            acc[1][0] = pmax(acc[1][0], pmin(a1, b0));
            acc[1][1] = pmax(acc[1][1], pmin(a1, b1));
            acc[2][0] = pmax(acc[2][0], pmin(a2, b0));
            acc[2][1] = pmax(acc[2][1], pmin(a2, b1));
            acc[3][0] = pmax(acc[3][0], pmin(a3, b0));
            acc[3][1] = pmax(acc[3][1], pmin(a3, b1));
        }
        __syncthreads();
    }

    // partial epilogue: reduce k-pair lanes, store fp16 partial max
    #pragma unroll
    for (int j = 0; j < 4; ++j) {
        const float n0 = fmaxf((float)acc[j][0][0], (float)acc[j][0][1]);
        const float n1 = fmaxf((float)acc[j][1][0], (float)acc[j][1][1]);
        const h2 pr = pack2(n0, n1);
        const int idx = ((p * SPLIT + sp) * SDIM + (s0 + sl + j)) * SDIM + o0 + ol;
        *reinterpret_cast<h2*>(part + idx) = pr;   // idx even -> 4B aligned
    }
}

__global__ __launch_bounds__(256) void finalize_kernel(
        const float* __restrict__ t, const _Float16* __restrict__ part,
        float* __restrict__ out) {
    const int i2 = blockIdx.x * 256 + threadIdx.x;   // float2 index over [2][512][256]
    const h2* __restrict__ ph = reinterpret_cast<const h2*>(part);
    const int ps = i2 >> 8;          // p*512 + s
    const int c2 = i2 & 255;
    const int p = ps >> 9, s = ps & 511;
    const int base = (p * SPLIT) * (SDIM * SDIM / 2) + s * (SDIM / 2) + c2;
    h2 m = ph[base];
    m = pmax(m, ph[base + 1 * (SDIM * SDIM / 2)]);
    m = pmax(m, ph[base + 2 * (SDIM * SDIM / 2)]);
    m = pmax(m, ph[base + 3 * (SDIM * SDIM / 2)]);
    const float2 tv = reinterpret_cast<const float2*>(t)[i2];
    const float n0 = (float)m[0], n1 = (float)m[1];
    float2 r;
    r.x = tv.x + n0 - tv.x * n0;
    r.y = tv.y + n1 - tv.y * n1;
    reinterpret_cast<float2*>(out)[i2] = r;
}

extern "C" void kernel_launch(void* const* d_in, const int* in_sizes, int n_in,
                              void* d_out, int out_size, void* d_ws, size_t ws_size,
                              hipStream_t stream) {
    const float* t = (const float*)d_in[0];
    float* out = (float*)d_out;
    _Float16* part = (_Float16*)d_ws;   // 2*4*512*512 fp16 = 4 MB

    dim3 grid1(SDIM / TO, SDIM / TS, 2 * SPLIT);   // 16 x 8 x 8 = 1024 blocks
    compose_part<<<grid1, 256, 0, stream>>>(t, part);

    const int n2 = 2 * SDIM * SDIM / 2;            // float2 elements
    finalize_kernel<<<n2 / 256, 256, 0, stream>>>(t, part, out);
}

// Round 5
// 69.548 us; speedup vs baseline: 1.9979x; 1.9979x over previous
//
#include <hip/hip_runtime.h>

// Fuzzy decoder: num[p,s,o] = max_k min(t0[s,k], t_p[k,o]); out = t + num - t*num.
// S=K=O=512, p in {0,1}. Packed-fp16 semiring GEMM (v_pk_min/v_pk_max), fp32 epilogue.
// Single kernel, NO workspace (R4 lesson: touching poisoned d_ws costs a 268MB
// writeback storm). Occupancy fix: 32x32 tiles, 2s x 2o per thread ->
// 512 blocks x 256 thr = 2 blocks/CU = 2 waves/SIMD.

#define SDIM 512
#define TS 32      // s-tile per block
#define TO 32      // o-tile per block
#define BK 64      // k per chunk
#define BK2 32     // packed k-pairs per chunk
#define NCH (SDIM / BK)   // 8 chunks
#define BSTR 36    // padded stride for Bls

typedef _Float16 h2 __attribute__((ext_vector_type(2)));

__device__ __forceinline__ h2 pack2(float a, float b) {
    return __builtin_bit_cast(h2, __builtin_amdgcn_cvt_pkrtz(a, b));  // v_cvt_pkrtz_f16_f32
}
__device__ __forceinline__ h2 pmin(h2 a, h2 b) { return __builtin_elementwise_min(a, b); }
__device__ __forceinline__ h2 pmax(h2 a, h2 b) { return __builtin_elementwise_max(a, b); }
__device__ __forceinline__ h2 bch2(unsigned u) { return __builtin_bit_cast(h2, u); }

__global__ __launch_bounds__(256, 2) void fuzzy_compose_kernel(
        const float* __restrict__ t, float* __restrict__ out) {
    // A transposed: AlsT[k2][s], cols XOR-swizzled by (k2>>2)<<2 -> conflict-free stores
    __shared__ h2 AlsT[BK2][TS];
    // B: Bls[k2][o], stride 36 -> b128 stores at data floor
    __shared__ h2 Bls[BK2][BSTR];

    const int tid = threadIdx.x;
    const int o0 = blockIdx.x * TO;   // 16 o-tiles
    const int s0 = blockIdx.y * TS;   // 16 s-tiles
    const int p  = blockIdx.z;        // 2 predicates

    const float* __restrict__ B = t + p * (SDIM * SDIM);

    // compute mapping: 2 s-rows x 2 o-cols per thread
    const int ol = (tid & 15) * 2, sl = (tid >> 4) * 2;
    // A staging: row ar (0..31), k-float4 pair aq (0..7)
    const int ar = tid >> 3, aq = tid & 7;
    const int acol = ar ^ (aq << 2);          // XOR swizzle: 2-way max on stores
    // B staging: k-pair bk2 (0..31), float4-col bq (0..7)
    const int bk2 = tid >> 3, bq = tid & 7;

    const float4* __restrict__ Arow =
        reinterpret_cast<const float4*>(t + (s0 + ar) * SDIM);

    h2 acc[2][2];
    acc[0][0] = pack2(0.f, 0.f); acc[0][1] = pack2(0.f, 0.f);
    acc[1][0] = pack2(0.f, 0.f); acc[1][1] = pack2(0.f, 0.f);

    float4 fa0, fa1, fx, fy;
    // prologue: load chunk 0 (A: f4 idx aq*2, aq*2+1; B: rows 2bk2,2bk2+1, f4-col bq)
    fa0 = Arow[aq * 2 + 0];
    fa1 = Arow[aq * 2 + 1];
    fx = *reinterpret_cast<const float4*>(B + (2 * bk2) * SDIM + o0 + bq * 4);
    fy = *reinterpret_cast<const float4*>(B + (2 * bk2 + 1) * SDIM + o0 + bq * 4);

    for (int c = 0; c < NCH; ++c) {
        // staged regs -> LDS
        {
            const int k2b = aq * 4;
            AlsT[k2b + 0][acol] = pack2(fa0.x, fa0.y);
            AlsT[k2b + 1][acol] = pack2(fa0.z, fa0.w);
            AlsT[k2b + 2][acol] = pack2(fa1.x, fa1.y);
            AlsT[k2b + 3][acol] = pack2(fa1.z, fa1.w);
            uint4 u;
            u.x = __builtin_bit_cast(unsigned, pack2(fx.x, fy.x));
            u.y = __builtin_bit_cast(unsigned, pack2(fx.y, fy.y));
            u.z = __builtin_bit_cast(unsigned, pack2(fx.z, fy.z));
            u.w = __builtin_bit_cast(unsigned, pack2(fx.w, fy.w));
            *reinterpret_cast<uint4*>(&Bls[bk2][bq * 4]) = u;  // one b128 store
        }
        __syncthreads();

        // prefetch next chunk (overlaps compute)
        if (c + 1 < NCH) {
            const int k0 = (c + 1) * BK;
            fa0 = Arow[k0 / 4 + aq * 2 + 0];
            fa1 = Arow[k0 / 4 + aq * 2 + 1];
            fx = *reinterpret_cast<const float4*>(B + (k0 + 2 * bk2) * SDIM + o0 + bq * 4);
            fy = *reinterpret_cast<const float4*>(B + (k0 + 2 * bk2 + 1) * SDIM + o0 + bq * 4);
        }

        // inner loop: per k2 = 1 b64 (A, swizzled) + 1 b64 (B) + 8 pk instrs
        #pragma unroll
        for (int k2 = 0; k2 < BK2; ++k2) {
            const int swz = ((k2 >> 2) & 7) << 2;
            const uint2 ua = *reinterpret_cast<const uint2*>(&AlsT[k2][sl ^ swz]);
            const uint2 ub = *reinterpret_cast<const uint2*>(&Bls[k2][ol]);
            const h2 a0 = bch2(ua.x), a1 = bch2(ua.y);
            const h2 b0 = bch2(ub.x), b1 = bch2(ub.y);
            acc[0][0] = pmax(acc[0][0], pmin(a0, b0));
            acc[0][1] = pmax(acc[0][1], pmin(a0, b1));
            acc[1][0] = pmax(acc[1][0], pmin(a1, b0));
            acc[1][1] = pmax(acc[1][1], pmin(a1, b1));
        }
        __syncthreads();
    }

    // fused epilogue: num = max of packed k-pair; out = t + num - t*num (fp32)
    const float* __restrict__ tp = t + p * (SDIM * SDIM);
    float* __restrict__ op = out + p * (SDIM * SDIM);
    #pragma unroll
    for (int j = 0; j < 2; ++j) {
        const int row = s0 + sl + j;
        const float2 tv = *reinterpret_cast<const float2*>(tp + row * SDIM + o0 + ol);
        const float n0 = fmaxf((float)acc[j][0][0], (float)acc[j][0][1]);
        const float n1 = fmaxf((float)acc[j][1][0], (float)acc[j][1][1]);
        float2 r;
        r.x = tv.x + n0 - tv.x * n0;
        r.y = tv.y + n1 - tv.y * n1;
        *reinterpret_cast<float2*>(op + row * SDIM + o0 + ol) = r;
    }
}

extern "C" void kernel_launch(void* const* d_in, const int* in_sizes, int n_in,
                              void* d_out, int out_size, void* d_ws, size_t ws_size,
                              hipStream_t stream) {
    const float* t = (const float*)d_in[0];
    float* out = (float*)d_out;
    dim3 grid(SDIM / TO, SDIM / TS, 2);   // 16 x 16 x 2 = 512 blocks
    fuzzy_compose_kernel<<<grid, 256, 0, stream>>>(t, out);
}